// Round 1
// baseline (4314.145 us; speedup 1.0000x reference)
//
#include <hip/hip_runtime.h>

#define NN 100000
#define NE 1600000
#define DIM 64

__global__ __launch_bounds__(256) void k_init_deg(float* deg, int n) {
    int i = blockIdx.x * 256 + threadIdx.x;
    if (i < n) deg[i] = 1.0f;  // self-loop weight
}

__global__ __launch_bounds__(256) void k_accum_deg(const int* __restrict__ dst,
                                                   const float* __restrict__ w,
                                                   float* deg, int e) {
    int i = blockIdx.x * 256 + threadIdx.x;
    if (i < e) atomicAdd(&deg[dst[i]], w[i]);
}

__global__ __launch_bounds__(256) void k_dinv(float* deg, int n) {
    int i = blockIdx.x * 256 + threadIdx.x;
    if (i < n) deg[i] = rsqrtf(deg[i]);  // deg >= 1 always
}

__global__ __launch_bounds__(256) void k_norm(const int* __restrict__ src,
                                              const int* __restrict__ dst,
                                              const float* __restrict__ w,
                                              const float* __restrict__ dinv,
                                              float* __restrict__ norm, int e) {
    int i = blockIdx.x * 256 + threadIdx.x;
    if (i < e) norm[i] = dinv[src[i]] * w[i] * dinv[dst[i]];
}

// H = X @ W ; OUT = H * dinv^2 + b   (self-loop + bias folded in)
// OUT may alias X: each block stages its 16 rows in LDS before writing.
__global__ __launch_bounds__(256) void k_gemm_fused(const float* __restrict__ X,
                                                    const float* __restrict__ W,
                                                    const float* __restrict__ bias,
                                                    const float* __restrict__ dinv,
                                                    float* __restrict__ H,
                                                    float* __restrict__ OUT, int n) {
    __shared__ float Ws[64][64];   // 16 KB
    __shared__ float Xs[16][64];   // 4 KB
    int tid = threadIdx.x;
    int row0 = blockIdx.x * 16;

    #pragma unroll
    for (int t = tid; t < 64 * 64; t += 256) Ws[t >> 6][t & 63] = W[t];
    #pragma unroll
    for (int t = tid; t < 16 * 64; t += 256) {
        int r = t >> 6, c = t & 63;
        int gr = row0 + r;
        Xs[r][c] = (gr < n) ? X[gr * DIM + c] : 0.0f;
    }
    __syncthreads();

    int col = tid & 63;
    int rbase = tid >> 6;  // wave-uniform
    #pragma unroll
    for (int rr = 0; rr < 4; rr++) {
        int r = rbase * 4 + rr;
        int gr = row0 + r;
        if (gr >= n) continue;
        float acc = 0.0f;
        #pragma unroll
        for (int k = 0; k < 64; k++) acc = fmaf(Xs[r][k], Ws[k][col], acc);
        H[gr * DIM + col] = acc;
        float dn = dinv[gr];
        OUT[gr * DIM + col] = acc * dn * dn + bias[col];
    }
}

// One edge per 16 lanes; float4 gather from H[src], 4 atomicAdds to OUT[dst].
__global__ __launch_bounds__(256) void k_scatter(const int* __restrict__ src,
                                                 const int* __restrict__ dst,
                                                 const float* __restrict__ norm,
                                                 const float* __restrict__ H,
                                                 float* __restrict__ OUT, int e) {
    int t = blockIdx.x * 256 + threadIdx.x;
    int edge = t >> 4;
    if (edge >= e) return;
    int lane = t & 15;
    int s = src[edge], d = dst[edge];
    float nm = norm[edge];
    const float4 hv = *reinterpret_cast<const float4*>(H + (size_t)s * DIM + lane * 4);
    float* outp = OUT + (size_t)d * DIM + lane * 4;
    atomicAdd(outp + 0, hv.x * nm);
    atomicAdd(outp + 1, hv.y * nm);
    atomicAdd(outp + 2, hv.z * nm);
    atomicAdd(outp + 3, hv.w * nm);
}

__global__ __launch_bounds__(256) void k_relu(float* a, int total) {
    int i = blockIdx.x * 256 + threadIdx.x;
    if (i < total) a[i] = fmaxf(a[i], 0.0f);
}

extern "C" void kernel_launch(void* const* d_in, const int* in_sizes, int n_in,
                              void* d_out, int out_size, void* d_ws, size_t ws_size,
                              hipStream_t stream) {
    const float* x   = (const float*)d_in[0];
    const int* ei    = (const int*)d_in[1];      // [2][NE] int32
    const float* ew  = (const float*)d_in[2];
    const float* W1  = (const float*)d_in[3];
    const float* b1  = (const float*)d_in[4];
    const float* W2  = (const float*)d_in[5];
    const float* b2  = (const float*)d_in[6];
    const float* W3  = (const float*)d_in[7];
    const float* b3  = (const float*)d_in[8];
    float* out = (float*)d_out;

    const int* src = ei;
    const int* dst = ei + NE;

    char* ws = (char*)d_ws;
    float* dinv = (float*)ws;                     ws += ((size_t)NN * 4 + 255) / 256 * 256;
    float* norm = (float*)ws;                     ws += ((size_t)NE * 4 + 255) / 256 * 256;
    float* H    = (float*)ws;                     ws += (size_t)NN * DIM * 4;
    float* TMP  = (float*)ws;

    const int gN   = (NN + 255) / 256;
    const int gE   = (NE + 255) / 256;
    const int gRow = (NN + 15) / 16;
    const int gSc  = (NE * 16) / 256;
    const int gEl  = (NN * DIM) / 256;

    // norm precompute
    k_init_deg<<<gN, 256, 0, stream>>>(dinv, NN);
    k_accum_deg<<<gE, 256, 0, stream>>>(dst, ew, dinv, NE);
    k_dinv<<<gN, 256, 0, stream>>>(dinv, NN);
    k_norm<<<gE, 256, 0, stream>>>(src, dst, ew, dinv, norm, NE);

    // layer 1
    k_gemm_fused<<<gRow, 256, 0, stream>>>(x, W1, b1, dinv, H, TMP, NN);
    k_scatter<<<gSc, 256, 0, stream>>>(src, dst, norm, H, TMP, NE);
    k_relu<<<gEl, 256, 0, stream>>>(TMP, NN * DIM);

    // layer 2 (gemm in-place on TMP is safe: rows staged in LDS per block)
    k_gemm_fused<<<gRow, 256, 0, stream>>>(TMP, W2, b2, dinv, H, TMP, NN);
    k_scatter<<<gSc, 256, 0, stream>>>(src, dst, norm, H, TMP, NE);
    k_relu<<<gEl, 256, 0, stream>>>(TMP, NN * DIM);

    // layer 3 -> d_out, no relu
    k_gemm_fused<<<gRow, 256, 0, stream>>>(TMP, W3, b3, dinv, H, out, NN);
    k_scatter<<<gSc, 256, 0, stream>>>(src, dst, norm, H, out, NE);
}

// Round 2
// 681.581 us; speedup vs baseline: 6.3296x; 6.3296x over previous
//
#include <hip/hip_runtime.h>

#define NN 100000
#define NE 1600000
#define DIM 64
#define SCAN_CHUNK 1024
#define NBLK_SCAN ((NN + SCAN_CHUNK - 1) / SCAN_CHUNK)   // 98

__global__ __launch_bounds__(256) void k_init_deg(float* deg, int n) {
    int i = blockIdx.x * 256 + threadIdx.x;
    if (i < n) deg[i] = 1.0f;  // self-loop weight
}

__global__ __launch_bounds__(256) void k_accum_deg(const int* __restrict__ dst,
                                                   const float* __restrict__ w,
                                                   float* deg, int e) {
    int i = blockIdx.x * 256 + threadIdx.x;
    if (i < e) atomicAdd(&deg[dst[i]], w[i]);
}

__global__ __launch_bounds__(256) void k_dinv(float* deg, int n) {
    int i = blockIdx.x * 256 + threadIdx.x;
    if (i < n) deg[i] = rsqrtf(deg[i]);  // deg >= 1 always
}

__global__ __launch_bounds__(256) void k_zero_counts(int* cnt, int n) {
    int i = blockIdx.x * 256 + threadIdx.x;
    if (i < n) cnt[i] = 0;
}

__global__ __launch_bounds__(256) void k_count(const int* __restrict__ dst, int* cnt, int e) {
    int i = blockIdx.x * 256 + threadIdx.x;
    if (i < e) atomicAdd(&cnt[dst[i]], 1);
}

// Per-block exclusive scan over SCAN_CHUNK counts; block-local result into row_ptr,
// block total into blocksums.
__global__ __launch_bounds__(256) void k_scan1(const int* __restrict__ cnt,
                                               int* __restrict__ row_ptr,
                                               int* __restrict__ blocksums, int n) {
    __shared__ int sd[256];
    int t = threadIdx.x;
    int base = blockIdx.x * SCAN_CHUNK + t * 4;
    int v[4], s = 0;
    #pragma unroll
    for (int i = 0; i < 4; i++) {
        int idx = base + i;
        v[i] = (idx < n) ? cnt[idx] : 0;
        s += v[i];
    }
    sd[t] = s;
    __syncthreads();
    #pragma unroll
    for (int off = 1; off < 256; off <<= 1) {
        int x = (t >= off) ? sd[t - off] : 0;
        __syncthreads();
        sd[t] += x;
        __syncthreads();
    }
    int excl = sd[t] - s;  // exclusive prefix of this thread's 4-group
    #pragma unroll
    for (int i = 0; i < 4; i++) {
        int idx = base + i;
        if (idx < n) row_ptr[idx] = excl;
        excl += v[i];
    }
    if (t == 255) blocksums[blockIdx.x] = sd[255];
}

// Serial exclusive scan of the 98 block sums (tiny). Also writes row_ptr[n] = total.
__global__ void k_scan2(int* blocksums, int* row_ptr, int nblk, int n) {
    if (threadIdx.x == 0 && blockIdx.x == 0) {
        int run = 0;
        for (int b = 0; b < nblk; b++) {
            int v = blocksums[b];
            blocksums[b] = run;
            run += v;
        }
        row_ptr[n] = run;  // == NE
    }
}

// Add block offsets; also initialize the placement cursor array.
__global__ __launch_bounds__(256) void k_scan3(int* __restrict__ row_ptr,
                                               int* __restrict__ fill,
                                               const int* __restrict__ blocksums, int n) {
    int i = blockIdx.x * 256 + threadIdx.x;
    if (i < n) {
        int v = row_ptr[i] + blocksums[i / SCAN_CHUNK];
        row_ptr[i] = v;
        fill[i] = v;
    }
}

// Place each edge into CSR order; compute norm inline.
__global__ __launch_bounds__(256) void k_place(const int* __restrict__ src,
                                               const int* __restrict__ dst,
                                               const float* __restrict__ w,
                                               const float* __restrict__ dinv,
                                               int* __restrict__ fill,
                                               int* __restrict__ src_sorted,
                                               float* __restrict__ norm_sorted, int e) {
    int i = blockIdx.x * 256 + threadIdx.x;
    if (i >= e) return;
    int s = src[i], d = dst[i];
    int pos = atomicAdd(&fill[d], 1);
    src_sorted[pos] = s;
    norm_sorted[pos] = dinv[s] * w[i] * dinv[d];
}

// H = X @ W  (64x64 weight staged in LDS; 16 rows per block)
__global__ __launch_bounds__(256) void k_gemm(const float* __restrict__ X,
                                              const float* __restrict__ W,
                                              float* __restrict__ H, int n) {
    __shared__ float Ws[64][64];
    __shared__ float Xs[16][64];
    int tid = threadIdx.x;
    int row0 = blockIdx.x * 16;

    #pragma unroll
    for (int t = tid; t < 64 * 64; t += 256) Ws[t >> 6][t & 63] = W[t];
    #pragma unroll
    for (int t = tid; t < 16 * 64; t += 256) {
        int r = t >> 6, c = t & 63;
        int gr = row0 + r;
        Xs[r][c] = (gr < n) ? X[gr * DIM + c] : 0.0f;
    }
    __syncthreads();

    int col = tid & 63;
    int rbase = tid >> 6;
    #pragma unroll
    for (int rr = 0; rr < 4; rr++) {
        int r = rbase * 4 + rr;
        int gr = row0 + r;
        if (gr >= n) continue;
        float acc = 0.0f;
        #pragma unroll
        for (int k = 0; k < 64; k++) acc = fmaf(Xs[r][k], Ws[k][col], acc);
        H[(size_t)gr * DIM + col] = acc;
    }
}

// Pull-aggregation: one wave per node, lane = channel.
// OUT[n][c] = sum_e norm[e]*H[src[e]][c] + H[n][c]*dinv[n]^2 + bias[c]  (+ReLU)
template <int RELU>
__global__ __launch_bounds__(256) void k_agg(const int* __restrict__ row_ptr,
                                             const int* __restrict__ src_sorted,
                                             const float* __restrict__ norm_sorted,
                                             const float* __restrict__ H,
                                             const float* __restrict__ bias,
                                             const float* __restrict__ dinv,
                                             float* __restrict__ OUT, int n) {
    int node = blockIdx.x * 4 + (threadIdx.x >> 6);
    int lane = threadIdx.x & 63;
    if (node >= n) return;
    int beg = row_ptr[node], end = row_ptr[node + 1];
    float acc = 0.0f;
    int e = beg;
    for (; e + 1 < end; e += 2) {
        int s0 = src_sorted[e], s1 = src_sorted[e + 1];
        float n0 = norm_sorted[e], n1 = norm_sorted[e + 1];
        float h0 = H[(size_t)s0 * DIM + lane];
        float h1 = H[(size_t)s1 * DIM + lane];
        acc = fmaf(n0, h0, acc);
        acc = fmaf(n1, h1, acc);
    }
    if (e < end) {
        int s0 = src_sorted[e];
        acc = fmaf(norm_sorted[e], H[(size_t)s0 * DIM + lane], acc);
    }
    float dn = dinv[node];
    acc = fmaf(H[(size_t)node * DIM + lane], dn * dn, acc);
    acc += bias[lane];
    if (RELU) acc = fmaxf(acc, 0.0f);
    OUT[(size_t)node * DIM + lane] = acc;
}

extern "C" void kernel_launch(void* const* d_in, const int* in_sizes, int n_in,
                              void* d_out, int out_size, void* d_ws, size_t ws_size,
                              hipStream_t stream) {
    const float* x  = (const float*)d_in[0];
    const int* ei   = (const int*)d_in[1];   // [2][NE] int32
    const float* ew = (const float*)d_in[2];
    const float* W1 = (const float*)d_in[3];
    const float* b1 = (const float*)d_in[4];
    const float* W2 = (const float*)d_in[5];
    const float* b2 = (const float*)d_in[6];
    const float* W3 = (const float*)d_in[7];
    const float* b3 = (const float*)d_in[8];
    float* out = (float*)d_out;

    const int* src = ei;
    const int* dst = ei + NE;

    auto align = [](size_t v) { return (v + 255) / 256 * 256; };
    char* ws = (char*)d_ws;
    float* dinv      = (float*)ws; ws += align((size_t)NN * 4);
    int*   row_ptr   = (int*)ws;   ws += align(((size_t)NN + 1) * 4);
    int*   counts    = (int*)ws;   ws += align((size_t)NN * 4);
    int*   fill      = (int*)ws;   ws += align((size_t)NN * 4);
    int*   blocksums = (int*)ws;   ws += align(256 * 4);
    int*   src_sorted  = (int*)ws;   ws += align((size_t)NE * 4);
    float* norm_sorted = (float*)ws; ws += align((size_t)NE * 4);
    float* H = (float*)ws;           ws += (size_t)NN * DIM * 4;
    float* A = (float*)ws;

    const int gN   = (NN + 255) / 256;
    const int gE   = (NE + 255) / 256;
    const int gRow = (NN + 15) / 16;
    const int gAgg = (NN + 3) / 4;

    // ---- norm precompute ----
    k_init_deg<<<gN, 256, 0, stream>>>(dinv, NN);
    k_accum_deg<<<gE, 256, 0, stream>>>(dst, ew, dinv, NE);
    k_dinv<<<gN, 256, 0, stream>>>(dinv, NN);

    // ---- CSR build (counting sort by dst) ----
    k_zero_counts<<<gN, 256, 0, stream>>>(counts, NN);
    k_count<<<gE, 256, 0, stream>>>(dst, counts, NE);
    k_scan1<<<NBLK_SCAN, 256, 0, stream>>>(counts, row_ptr, blocksums, NN);
    k_scan2<<<1, 64, 0, stream>>>(blocksums, row_ptr, NBLK_SCAN, NN);
    k_scan3<<<gN, 256, 0, stream>>>(row_ptr, fill, blocksums, NN);
    k_place<<<gE, 256, 0, stream>>>(src, dst, ew, dinv, fill, src_sorted, norm_sorted, NE);

    // ---- layer 1 ----
    k_gemm<<<gRow, 256, 0, stream>>>(x, W1, H, NN);
    k_agg<1><<<gAgg, 256, 0, stream>>>(row_ptr, src_sorted, norm_sorted, H, b1, dinv, A, NN);
    // ---- layer 2 ----
    k_gemm<<<gRow, 256, 0, stream>>>(A, W2, H, NN);
    k_agg<1><<<gAgg, 256, 0, stream>>>(row_ptr, src_sorted, norm_sorted, H, b2, dinv, A, NN);
    // ---- layer 3 ----
    k_gemm<<<gRow, 256, 0, stream>>>(A, W3, H, NN);
    k_agg<0><<<gAgg, 256, 0, stream>>>(row_ptr, src_sorted, norm_sorted, H, b3, dinv, out, NN);
}

// Round 3
// 491.200 us; speedup vs baseline: 8.7829x; 1.3876x over previous
//
#include <hip/hip_runtime.h>

#define NN 100000
#define NE 1600000
#define DIM 64
#define SCAN_CHUNK 1024
#define NBLK_SCAN ((NN + SCAN_CHUNK - 1) / SCAN_CHUNK)   // 98

// deg = 1 (self-loop), counts = 0
__global__ __launch_bounds__(256) void k_init(float* deg, int* cnt, int n) {
    int i = blockIdx.x * 256 + threadIdx.x;
    if (i < n) { deg[i] = 1.0f; cnt[i] = 0; }
}

// one edge pass: weighted in-degree + in-count
__global__ __launch_bounds__(256) void k_edge1(const int* __restrict__ dst,
                                               const float* __restrict__ w,
                                               float* deg, int* cnt, int e) {
    int i = blockIdx.x * 256 + threadIdx.x;
    if (i < e) {
        int d = dst[i];
        atomicAdd(&deg[d], w[i]);
        atomicAdd(&cnt[d], 1);
    }
}

__global__ __launch_bounds__(256) void k_dinv(float* deg, int n) {
    int i = blockIdx.x * 256 + threadIdx.x;
    if (i < n) deg[i] = rsqrtf(deg[i]);  // deg >= 1 always
}

// Per-block exclusive scan over SCAN_CHUNK counts.
__global__ __launch_bounds__(256) void k_scan1(const int* __restrict__ cnt,
                                               int* __restrict__ row_ptr,
                                               int* __restrict__ blocksums, int n) {
    __shared__ int sd[256];
    int t = threadIdx.x;
    int base = blockIdx.x * SCAN_CHUNK + t * 4;
    int v[4], s = 0;
    #pragma unroll
    for (int i = 0; i < 4; i++) {
        int idx = base + i;
        v[i] = (idx < n) ? cnt[idx] : 0;
        s += v[i];
    }
    sd[t] = s;
    __syncthreads();
    #pragma unroll
    for (int off = 1; off < 256; off <<= 1) {
        int x = (t >= off) ? sd[t - off] : 0;
        __syncthreads();
        sd[t] += x;
        __syncthreads();
    }
    int excl = sd[t] - s;
    #pragma unroll
    for (int i = 0; i < 4; i++) {
        int idx = base + i;
        if (idx < n) row_ptr[idx] = excl;
        excl += v[i];
    }
    if (t == 255) blocksums[blockIdx.x] = sd[255];
}

// Parallel exclusive scan of the (<=128) block sums; writes row_ptr[n] = total.
__global__ __launch_bounds__(128) void k_scan2(int* blocksums, int* row_ptr, int nblk, int n) {
    __shared__ int sd[128];
    int t = threadIdx.x;
    int v = (t < nblk) ? blocksums[t] : 0;
    sd[t] = v;
    __syncthreads();
    #pragma unroll
    for (int off = 1; off < 128; off <<= 1) {
        int x = (t >= off) ? sd[t - off] : 0;
        __syncthreads();
        sd[t] += x;
        __syncthreads();
    }
    if (t < nblk) blocksums[t] = sd[t] - v;   // exclusive
    if (t == nblk - 1) row_ptr[n] = sd[t];    // total == NE
}

__global__ __launch_bounds__(256) void k_scan3(int* __restrict__ row_ptr,
                                               int* __restrict__ fill,
                                               const int* __restrict__ blocksums, int n) {
    int i = blockIdx.x * 256 + threadIdx.x;
    if (i < n) {
        int v = row_ptr[i] + blocksums[i / SCAN_CHUNK];
        row_ptr[i] = v;
        fill[i] = v;
    }
}

// Place each edge into CSR order; packed (src, norm) single 8B store.
__global__ __launch_bounds__(256) void k_place(const int* __restrict__ src,
                                               const int* __restrict__ dst,
                                               const float* __restrict__ w,
                                               const float* __restrict__ dinv,
                                               int* __restrict__ fill,
                                               int2* __restrict__ edata, int e) {
    int i = blockIdx.x * 256 + threadIdx.x;
    if (i >= e) return;
    int s = src[i], d = dst[i];
    int pos = atomicAdd(&fill[d], 1);
    float nm = dinv[s] * w[i] * dinv[d];
    edata[pos] = make_int2(s, __float_as_int(nm));
}

// Fused layer: OUT[v] = act( (sum_e norm*Aprev[src] + dinv[v]^2*Aprev[v]) @ W + b )
// Uses A_hat(X W) == (A_hat X) W. One wave per node; weight column in registers.
template <int RELU>
__global__ __launch_bounds__(256) void k_layer(const int* __restrict__ row_ptr,
                                               const int2* __restrict__ edata,
                                               const float* __restrict__ Aprev,
                                               const float* __restrict__ W,
                                               const float* __restrict__ bias,
                                               const float* __restrict__ dinv,
                                               float* __restrict__ Anext, int n) {
    __shared__ float rowbuf[4][64];
    int tid = threadIdx.x;
    int lane = tid & 63;
    int wv = tid >> 6;

    // my output column of W, held in registers (read from L2, W is hot)
    float wcol[64];
    #pragma unroll
    for (int k = 0; k < 64; k++) wcol[k] = W[k * 64 + lane];
    float bl = bias[lane];

    int g = lane >> 4;   // edge group 0..3
    int l = lane & 15;   // lane in group; channels 4l..4l+3

    int wave_id = blockIdx.x * 4 + wv;
    int nwaves = gridDim.x * 4;

    for (int node = wave_id; node < n; node += nwaves) {
        int beg = row_ptr[node], end = row_ptr[node + 1];
        float4 acc = make_float4(0.f, 0.f, 0.f, 0.f);

        int e = beg + g;
        for (; e + 4 < end; e += 8) {   // 2 edges in flight per group
            int2 e0 = edata[e];
            int2 e1 = edata[e + 4];
            float n0 = __int_as_float(e0.y);
            float n1 = __int_as_float(e1.y);
            float4 h0 = *reinterpret_cast<const float4*>(Aprev + (size_t)e0.x * DIM + l * 4);
            float4 h1 = *reinterpret_cast<const float4*>(Aprev + (size_t)e1.x * DIM + l * 4);
            acc.x = fmaf(n0, h0.x, acc.x); acc.y = fmaf(n0, h0.y, acc.y);
            acc.z = fmaf(n0, h0.z, acc.z); acc.w = fmaf(n0, h0.w, acc.w);
            acc.x = fmaf(n1, h1.x, acc.x); acc.y = fmaf(n1, h1.y, acc.y);
            acc.z = fmaf(n1, h1.z, acc.z); acc.w = fmaf(n1, h1.w, acc.w);
        }
        if (e < end) {
            int2 e0 = edata[e];
            float n0 = __int_as_float(e0.y);
            float4 h0 = *reinterpret_cast<const float4*>(Aprev + (size_t)e0.x * DIM + l * 4);
            acc.x = fmaf(n0, h0.x, acc.x); acc.y = fmaf(n0, h0.y, acc.y);
            acc.z = fmaf(n0, h0.z, acc.z); acc.w = fmaf(n0, h0.w, acc.w);
        }

        // reduce the 4 edge-groups (xor 16 then 32): every lane gets full sum
        acc.x += __shfl_xor(acc.x, 16); acc.y += __shfl_xor(acc.y, 16);
        acc.z += __shfl_xor(acc.z, 16); acc.w += __shfl_xor(acc.w, 16);
        acc.x += __shfl_xor(acc.x, 32); acc.y += __shfl_xor(acc.y, 32);
        acc.z += __shfl_xor(acc.z, 32); acc.w += __shfl_xor(acc.w, 32);

        if (g == 0) {  // self-loop + stash row in LDS
            float dn = dinv[node];
            float sc = dn * dn;
            float4 sv = *reinterpret_cast<const float4*>(Aprev + (size_t)node * DIM + l * 4);
            acc.x = fmaf(sc, sv.x, acc.x); acc.y = fmaf(sc, sv.y, acc.y);
            acc.z = fmaf(sc, sv.z, acc.z); acc.w = fmaf(sc, sv.w, acc.w);
            *reinterpret_cast<float4*>(&rowbuf[wv][l * 4]) = acc;
        }
        __builtin_amdgcn_wave_barrier();  // order LDS write -> read within wave

        // row @ W  (rowbuf reads are wave-broadcast; W column is in registers)
        float o = 0.f;
        #pragma unroll
        for (int k4 = 0; k4 < 16; k4++) {
            float4 r = *reinterpret_cast<const float4*>(&rowbuf[wv][k4 * 4]);
            o = fmaf(r.x, wcol[k4 * 4 + 0], o);
            o = fmaf(r.y, wcol[k4 * 4 + 1], o);
            o = fmaf(r.z, wcol[k4 * 4 + 2], o);
            o = fmaf(r.w, wcol[k4 * 4 + 3], o);
        }
        __builtin_amdgcn_wave_barrier();  // keep reads before next iter's write
        o += bl;
        if (RELU) o = fmaxf(o, 0.f);
        Anext[(size_t)node * DIM + lane] = o;
    }
}

extern "C" void kernel_launch(void* const* d_in, const int* in_sizes, int n_in,
                              void* d_out, int out_size, void* d_ws, size_t ws_size,
                              hipStream_t stream) {
    const float* x  = (const float*)d_in[0];
    const int* ei   = (const int*)d_in[1];   // [2][NE] int32
    const float* ew = (const float*)d_in[2];
    const float* W1 = (const float*)d_in[3];
    const float* b1 = (const float*)d_in[4];
    const float* W2 = (const float*)d_in[5];
    const float* b2 = (const float*)d_in[6];
    const float* W3 = (const float*)d_in[7];
    const float* b3 = (const float*)d_in[8];
    float* out = (float*)d_out;

    const int* src = ei;
    const int* dst = ei + NE;

    auto align = [](size_t v) { return (v + 255) / 256 * 256; };
    char* ws = (char*)d_ws;
    float* dinv      = (float*)ws; ws += align((size_t)NN * 4);
    int*   row_ptr   = (int*)ws;   ws += align(((size_t)NN + 1) * 4);
    int*   counts    = (int*)ws;   ws += align((size_t)NN * 4);
    int*   fill      = (int*)ws;   ws += align((size_t)NN * 4);
    int*   blocksums = (int*)ws;   ws += align(256 * 4);
    int2*  edata     = (int2*)ws;  ws += align((size_t)NE * 8);
    float* A1 = (float*)ws;        ws += (size_t)NN * DIM * 4;
    float* A2 = (float*)ws;

    const int gN = (NN + 255) / 256;
    const int gE = (NE + 255) / 256;
    const int gL = 2048;

    // ---- degree + CSR counting ----
    k_init<<<gN, 256, 0, stream>>>(dinv, counts, NN);
    k_edge1<<<gE, 256, 0, stream>>>(dst, ew, dinv, counts, NE);
    k_dinv<<<gN, 256, 0, stream>>>(dinv, NN);
    k_scan1<<<NBLK_SCAN, 256, 0, stream>>>(counts, row_ptr, blocksums, NN);
    k_scan2<<<1, 128, 0, stream>>>(blocksums, row_ptr, NBLK_SCAN, NN);
    k_scan3<<<gN, 256, 0, stream>>>(row_ptr, fill, blocksums, NN);
    k_place<<<gE, 256, 0, stream>>>(src, dst, ew, dinv, fill, edata, NE);

    // ---- fused layers: aggregate(prev) then transform ----
    k_layer<1><<<gL, 256, 0, stream>>>(row_ptr, edata, x,  W1, b1, dinv, A1, NN);
    k_layer<1><<<gL, 256, 0, stream>>>(row_ptr, edata, A1, W2, b2, dinv, A2, NN);
    k_layer<0><<<gL, 256, 0, stream>>>(row_ptr, edata, A2, W3, b3, dinv, out, NN);
}

// Round 4
// 412.302 us; speedup vs baseline: 10.4636x; 1.1914x over previous
//
#include <hip/hip_runtime.h>

#define NN 100000
#define NE 1600000
#define DIM 64
#define SCAN_CHUNK 1024
#define NBLK_SCAN ((NN + SCAN_CHUNK - 1) / SCAN_CHUNK)   // 98
#define FP_SCALE 16777216.0f            // 2^24 fixed-point for edge weights
#define FP_INV   5.9604644775390625e-8f // 2^-24

// packed[i] = (count << 40) | fixedpoint_sum(w)
__global__ __launch_bounds__(256) void k_init(unsigned long long* packed, int n) {
    int i = blockIdx.x * 256 + threadIdx.x;
    if (i < n) packed[i] = 0ULL;
}

// one edge pass, ONE 8B atomic: weighted in-degree (fixed point) + in-count
__global__ __launch_bounds__(256) void k_edge1(const int* __restrict__ dst,
                                               const float* __restrict__ w,
                                               unsigned long long* packed, int e) {
    int i = blockIdx.x * 256 + threadIdx.x;
    if (i < e) {
        unsigned long long add =
            (1ULL << 40) | (unsigned long long)__float2uint_rn(w[i] * FP_SCALE);
        atomicAdd(&packed[dst[i]], add);
    }
}

// unpack: dinv = rsqrt(1 + sum_w), cnt
__global__ __launch_bounds__(256) void k_unpack(const unsigned long long* __restrict__ packed,
                                                float* __restrict__ dinv,
                                                int* __restrict__ cnt, int n) {
    int i = blockIdx.x * 256 + threadIdx.x;
    if (i < n) {
        unsigned long long p = packed[i];
        cnt[i] = (int)(p >> 40);
        float sw = (float)(p & ((1ULL << 40) - 1)) * FP_INV;
        dinv[i] = rsqrtf(1.0f + sw);
    }
}

// Per-block exclusive scan over SCAN_CHUNK counts.
__global__ __launch_bounds__(256) void k_scan1(const int* __restrict__ cnt,
                                               int* __restrict__ row_ptr,
                                               int* __restrict__ blocksums, int n) {
    __shared__ int sd[256];
    int t = threadIdx.x;
    int base = blockIdx.x * SCAN_CHUNK + t * 4;
    int v[4], s = 0;
    #pragma unroll
    for (int i = 0; i < 4; i++) {
        int idx = base + i;
        v[i] = (idx < n) ? cnt[idx] : 0;
        s += v[i];
    }
    sd[t] = s;
    __syncthreads();
    #pragma unroll
    for (int off = 1; off < 256; off <<= 1) {
        int x = (t >= off) ? sd[t - off] : 0;
        __syncthreads();
        sd[t] += x;
        __syncthreads();
    }
    int excl = sd[t] - s;
    #pragma unroll
    for (int i = 0; i < 4; i++) {
        int idx = base + i;
        if (idx < n) row_ptr[idx] = excl;
        excl += v[i];
    }
    if (t == 255) blocksums[blockIdx.x] = sd[255];
}

// Parallel exclusive scan of the (<=128) block sums; writes row_ptr[n] = total.
__global__ __launch_bounds__(128) void k_scan2(int* blocksums, int* row_ptr, int nblk, int n) {
    __shared__ int sd[128];
    int t = threadIdx.x;
    int v = (t < nblk) ? blocksums[t] : 0;
    sd[t] = v;
    __syncthreads();
    #pragma unroll
    for (int off = 1; off < 128; off <<= 1) {
        int x = (t >= off) ? sd[t - off] : 0;
        __syncthreads();
        sd[t] += x;
        __syncthreads();
    }
    if (t < nblk) blocksums[t] = sd[t] - v;
    if (t == nblk - 1) row_ptr[n] = sd[t];
}

__global__ __launch_bounds__(256) void k_scan3(int* __restrict__ row_ptr,
                                               int* __restrict__ fill,
                                               const int* __restrict__ blocksums, int n) {
    int i = blockIdx.x * 256 + threadIdx.x;
    if (i < n) {
        int v = row_ptr[i] + blocksums[i / SCAN_CHUNK];
        row_ptr[i] = v;
        fill[i] = v;
    }
}

// Place each edge into CSR order; packed (src, norm) single 8B store.
__global__ __launch_bounds__(256) void k_place(const int* __restrict__ src,
                                               const int* __restrict__ dst,
                                               const float* __restrict__ w,
                                               const float* __restrict__ dinv,
                                               int* __restrict__ fill,
                                               int2* __restrict__ edata, int e) {
    int i = blockIdx.x * 256 + threadIdx.x;
    if (i >= e) return;
    int s = src[i], d = dst[i];
    int pos = atomicAdd(&fill[d], 1);
    float nm = dinv[s] * w[i] * dinv[d];
    edata[pos] = make_int2(s, __float_as_int(nm));
}

#define FMA4(acc, nm, h) \
    acc.x = fmaf(nm, h.x, acc.x); acc.y = fmaf(nm, h.y, acc.y); \
    acc.z = fmaf(nm, h.z, acc.z); acc.w = fmaf(nm, h.w, acc.w);

// Fused layer: OUT[v] = act( (sum_e norm*Aprev[src] + dinv[v]^2*Aprev[v]) @ W + b )
template <int RELU>
__global__ __launch_bounds__(256) void k_layer(const int* __restrict__ row_ptr,
                                               const int2* __restrict__ edata,
                                               const float* __restrict__ Aprev,
                                               const float* __restrict__ W,
                                               const float* __restrict__ bias,
                                               const float* __restrict__ dinv,
                                               float* __restrict__ Anext, int n) {
    __shared__ float rowbuf[4][64];
    int tid = threadIdx.x;
    int lane = tid & 63;
    int wv = tid >> 6;

    float wcol[64];
    #pragma unroll
    for (int k = 0; k < 64; k++) wcol[k] = W[k * 64 + lane];
    float bl = bias[lane];

    int g = lane >> 4;   // edge group 0..3
    int l = lane & 15;   // lane in group; channels 4l..4l+3

    int wave_id = blockIdx.x * 4 + wv;
    int nwaves = gridDim.x * 4;

    for (int node = wave_id; node < n; node += nwaves) {
        int beg = row_ptr[node], end = row_ptr[node + 1];
        float4 acc = make_float4(0.f, 0.f, 0.f, 0.f);

        int e = beg + g;
        // 4 edges in flight per group
        for (; e + 12 < end; e += 16) {
            int2 e0 = edata[e];
            int2 e1 = edata[e + 4];
            int2 e2 = edata[e + 8];
            int2 e3 = edata[e + 12];
            float4 h0 = *reinterpret_cast<const float4*>(Aprev + (size_t)e0.x * DIM + l * 4);
            float4 h1 = *reinterpret_cast<const float4*>(Aprev + (size_t)e1.x * DIM + l * 4);
            float4 h2 = *reinterpret_cast<const float4*>(Aprev + (size_t)e2.x * DIM + l * 4);
            float4 h3 = *reinterpret_cast<const float4*>(Aprev + (size_t)e3.x * DIM + l * 4);
            float n0 = __int_as_float(e0.y), n1 = __int_as_float(e1.y);
            float n2 = __int_as_float(e2.y), n3 = __int_as_float(e3.y);
            FMA4(acc, n0, h0); FMA4(acc, n1, h1);
            FMA4(acc, n2, h2); FMA4(acc, n3, h3);
        }
        // 2 in flight
        for (; e + 4 < end; e += 8) {
            int2 e0 = edata[e];
            int2 e1 = edata[e + 4];
            float4 h0 = *reinterpret_cast<const float4*>(Aprev + (size_t)e0.x * DIM + l * 4);
            float4 h1 = *reinterpret_cast<const float4*>(Aprev + (size_t)e1.x * DIM + l * 4);
            float n0 = __int_as_float(e0.y), n1 = __int_as_float(e1.y);
            FMA4(acc, n0, h0); FMA4(acc, n1, h1);
        }
        if (e < end) {
            int2 e0 = edata[e];
            float n0 = __int_as_float(e0.y);
            float4 h0 = *reinterpret_cast<const float4*>(Aprev + (size_t)e0.x * DIM + l * 4);
            FMA4(acc, n0, h0);
        }

        // reduce the 4 edge-groups; every lane ends with the full sum
        acc.x += __shfl_xor(acc.x, 16); acc.y += __shfl_xor(acc.y, 16);
        acc.z += __shfl_xor(acc.z, 16); acc.w += __shfl_xor(acc.w, 16);
        acc.x += __shfl_xor(acc.x, 32); acc.y += __shfl_xor(acc.y, 32);
        acc.z += __shfl_xor(acc.z, 32); acc.w += __shfl_xor(acc.w, 32);

        if (g == 0) {  // self-loop + stash row in LDS
            float dn = dinv[node];
            float sc = dn * dn;
            float4 sv = *reinterpret_cast<const float4*>(Aprev + (size_t)node * DIM + l * 4);
            FMA4(acc, sc, sv);
            *reinterpret_cast<float4*>(&rowbuf[wv][l * 4]) = acc;
        }
        __builtin_amdgcn_wave_barrier();

        // row @ W  (rowbuf LDS broadcast; W column in registers)
        float o = 0.f;
        #pragma unroll
        for (int k4 = 0; k4 < 16; k4++) {
            float4 r = *reinterpret_cast<const float4*>(&rowbuf[wv][k4 * 4]);
            o = fmaf(r.x, wcol[k4 * 4 + 0], o);
            o = fmaf(r.y, wcol[k4 * 4 + 1], o);
            o = fmaf(r.z, wcol[k4 * 4 + 2], o);
            o = fmaf(r.w, wcol[k4 * 4 + 3], o);
        }
        __builtin_amdgcn_wave_barrier();
        o += bl;
        if (RELU) o = fmaxf(o, 0.f);
        Anext[(size_t)node * DIM + lane] = o;
    }
}

extern "C" void kernel_launch(void* const* d_in, const int* in_sizes, int n_in,
                              void* d_out, int out_size, void* d_ws, size_t ws_size,
                              hipStream_t stream) {
    const float* x  = (const float*)d_in[0];
    const int* ei   = (const int*)d_in[1];   // [2][NE] int32
    const float* ew = (const float*)d_in[2];
    const float* W1 = (const float*)d_in[3];
    const float* b1 = (const float*)d_in[4];
    const float* W2 = (const float*)d_in[5];
    const float* b2 = (const float*)d_in[6];
    const float* W3 = (const float*)d_in[7];
    const float* b3 = (const float*)d_in[8];
    float* out = (float*)d_out;

    const int* src = ei;
    const int* dst = ei + NE;

    auto align = [](size_t v) { return (v + 255) / 256 * 256; };
    char* ws = (char*)d_ws;
    unsigned long long* packed = (unsigned long long*)ws; ws += align((size_t)NN * 8);
    float* dinv      = (float*)ws; ws += align((size_t)NN * 4);
    int*   row_ptr   = (int*)ws;   ws += align(((size_t)NN + 1) * 4);
    int*   counts    = (int*)ws;   ws += align((size_t)NN * 4);
    int*   fill      = (int*)ws;   ws += align((size_t)NN * 4);
    int*   blocksums = (int*)ws;   ws += align(256 * 4);
    int2*  edata     = (int2*)ws;  ws += align((size_t)NE * 8);
    float* A1 = (float*)ws;        ws += (size_t)NN * DIM * 4;
    float* A2 = (float*)ws;

    const int gN = (NN + 255) / 256;
    const int gE = (NE + 255) / 256;
    const int gL = 2048;

    // ---- degree + CSR counting (one 8B atomic per edge) ----
    k_init<<<gN, 256, 0, stream>>>(packed, NN);
    k_edge1<<<gE, 256, 0, stream>>>(dst, ew, packed, NE);
    k_unpack<<<gN, 256, 0, stream>>>(packed, dinv, counts, NN);
    k_scan1<<<NBLK_SCAN, 256, 0, stream>>>(counts, row_ptr, blocksums, NN);
    k_scan2<<<1, 128, 0, stream>>>(blocksums, row_ptr, NBLK_SCAN, NN);
    k_scan3<<<gN, 256, 0, stream>>>(row_ptr, fill, blocksums, NN);
    k_place<<<gE, 256, 0, stream>>>(src, dst, ew, dinv, fill, edata, NE);

    // ---- fused layers ----
    k_layer<1><<<gL, 256, 0, stream>>>(row_ptr, edata, x,  W1, b1, dinv, A1, NN);
    k_layer<1><<<gL, 256, 0, stream>>>(row_ptr, edata, A1, W2, b2, dinv, A2, NN);
    k_layer<0><<<gL, 256, 0, stream>>>(row_ptr, edata, A2, W3, b3, dinv, out, NN);
}

// Round 5
// 380.064 us; speedup vs baseline: 11.3511x; 1.0848x over previous
//
#include <hip/hip_runtime.h>

#define NN 100000
#define NE 1600000
#define DIM 64
#define CAP 48   // max in-degree bucket capacity; P(deg>=48 | lambda=16) ~ 1e-9/node

// fill[i] = i*CAP (bucket cursor start)
__global__ __launch_bounds__(256) void k_fill_init(int* fill, int n) {
    int i = blockIdx.x * 256 + threadIdx.x;
    if (i < n) fill[i] = i * CAP;
}

// Scatter each edge into its dst bucket: (src, w) packed 8B. One atomic per edge.
__global__ __launch_bounds__(256) void k_place(const int* __restrict__ src,
                                               const int* __restrict__ dst,
                                               const float* __restrict__ w,
                                               int* __restrict__ fill,
                                               int2* __restrict__ bucket, int e) {
    int i = blockIdx.x * 256 + threadIdx.x;
    if (i >= e) return;
    int d = dst[i];
    int pos = atomicAdd(&fill[d], 1);
    if (pos < d * CAP + CAP)  // clamp: never corrupt memory on (astronomically rare) overflow
        bucket[pos] = make_int2(src[i], __float_as_int(w[i]));
}

// dinv[i] = rsqrt(1 + sum_w over bucket i). 16 lanes per node, contiguous reads, no atomics.
__global__ __launch_bounds__(256) void k_deg(const int2* __restrict__ bucket,
                                             const int* __restrict__ fill,
                                             float* __restrict__ dinv, int n) {
    int gid = (blockIdx.x * 256 + threadIdx.x) >> 4;
    int l = threadIdx.x & 15;
    if (gid >= n) return;
    int base = gid * CAP;
    int cnt = min(fill[gid] - base, CAP);
    float s = 0.f;
    for (int j = l; j < cnt; j += 16) s += __int_as_float(bucket[base + j].y);
    s += __shfl_xor(s, 1); s += __shfl_xor(s, 2);
    s += __shfl_xor(s, 4); s += __shfl_xor(s, 8);
    if (l == 0) dinv[gid] = rsqrtf(1.0f + s);
}

#define FMA4(acc, nm, h) \
    acc.x = fmaf(nm, h.x, acc.x); acc.y = fmaf(nm, h.y, acc.y); \
    acc.z = fmaf(nm, h.z, acc.z); acc.w = fmaf(nm, h.w, acc.w);

// Fused layer: OUT[v] = act( dinv[v]*(sum_e dinv[s]*w*Aprev[s]) + dinv[v]^2*Aprev[v] ) @ W + b
// One wave per node; 4 edge-groups of 16 lanes; W column held in registers.
template <int RELU>
__global__ __launch_bounds__(256) void k_layer(const int* __restrict__ fill,
                                               const int2* __restrict__ bucket,
                                               const float* __restrict__ Aprev,
                                               const float* __restrict__ W,
                                               const float* __restrict__ bias,
                                               const float* __restrict__ dinv,
                                               float* __restrict__ Anext, int n) {
    __shared__ float rowbuf[4][64];
    int tid = threadIdx.x;
    int lane = tid & 63;
    int wv = tid >> 6;

    float wcol[64];
    #pragma unroll
    for (int k = 0; k < 64; k++) wcol[k] = W[k * 64 + lane];
    float bl = bias[lane];

    int g = lane >> 4;   // edge group 0..3
    int l = lane & 15;   // lane in group; channels 4l..4l+3

    int wave_id = blockIdx.x * 4 + wv;
    int nwaves = gridDim.x * 4;

    for (int node = wave_id; node < n; node += nwaves) {
        int base = node * CAP;
        int cnt = min(fill[node] - base, CAP);
        int end = base + cnt;
        float4 acc = make_float4(0.f, 0.f, 0.f, 0.f);

        int e = base + g;
        for (; e + 12 < end; e += 16) {   // 4 edges in flight per group
            int2 e0 = bucket[e];
            int2 e1 = bucket[e + 4];
            int2 e2 = bucket[e + 8];
            int2 e3 = bucket[e + 12];
            float d0 = dinv[e0.x], d1 = dinv[e1.x], d2 = dinv[e2.x], d3 = dinv[e3.x];
            float4 h0 = *reinterpret_cast<const float4*>(Aprev + (size_t)e0.x * DIM + l * 4);
            float4 h1 = *reinterpret_cast<const float4*>(Aprev + (size_t)e1.x * DIM + l * 4);
            float4 h2 = *reinterpret_cast<const float4*>(Aprev + (size_t)e2.x * DIM + l * 4);
            float4 h3 = *reinterpret_cast<const float4*>(Aprev + (size_t)e3.x * DIM + l * 4);
            float n0 = d0 * __int_as_float(e0.y), n1 = d1 * __int_as_float(e1.y);
            float n2 = d2 * __int_as_float(e2.y), n3 = d3 * __int_as_float(e3.y);
            FMA4(acc, n0, h0); FMA4(acc, n1, h1);
            FMA4(acc, n2, h2); FMA4(acc, n3, h3);
        }
        for (; e + 4 < end; e += 8) {     // 2 in flight
            int2 e0 = bucket[e];
            int2 e1 = bucket[e + 4];
            float d0 = dinv[e0.x], d1 = dinv[e1.x];
            float4 h0 = *reinterpret_cast<const float4*>(Aprev + (size_t)e0.x * DIM + l * 4);
            float4 h1 = *reinterpret_cast<const float4*>(Aprev + (size_t)e1.x * DIM + l * 4);
            float n0 = d0 * __int_as_float(e0.y), n1 = d1 * __int_as_float(e1.y);
            FMA4(acc, n0, h0); FMA4(acc, n1, h1);
        }
        if (e < end) {
            int2 e0 = bucket[e];
            float n0 = dinv[e0.x] * __int_as_float(e0.y);
            float4 h0 = *reinterpret_cast<const float4*>(Aprev + (size_t)e0.x * DIM + l * 4);
            FMA4(acc, n0, h0);
        }

        // reduce 4 edge-groups; every lane gets the full sum
        acc.x += __shfl_xor(acc.x, 16); acc.y += __shfl_xor(acc.y, 16);
        acc.z += __shfl_xor(acc.z, 16); acc.w += __shfl_xor(acc.w, 16);
        acc.x += __shfl_xor(acc.x, 32); acc.y += __shfl_xor(acc.y, 32);
        acc.z += __shfl_xor(acc.z, 32); acc.w += __shfl_xor(acc.w, 32);

        if (g == 0) {  // scale by dinv[d], add self-loop, stash row in LDS
            float dn = dinv[node];
            float4 sv = *reinterpret_cast<const float4*>(Aprev + (size_t)node * DIM + l * 4);
            acc.x = (fmaf(dn, sv.x, acc.x)) * dn;
            acc.y = (fmaf(dn, sv.y, acc.y)) * dn;
            acc.z = (fmaf(dn, sv.z, acc.z)) * dn;
            acc.w = (fmaf(dn, sv.w, acc.w)) * dn;
            *reinterpret_cast<float4*>(&rowbuf[wv][l * 4]) = acc;
        }
        __builtin_amdgcn_wave_barrier();

        // row @ W  (rowbuf LDS broadcast; W column in registers)
        float o = 0.f;
        #pragma unroll
        for (int k4 = 0; k4 < 16; k4++) {
            float4 r = *reinterpret_cast<const float4*>(&rowbuf[wv][k4 * 4]);
            o = fmaf(r.x, wcol[k4 * 4 + 0], o);
            o = fmaf(r.y, wcol[k4 * 4 + 1], o);
            o = fmaf(r.z, wcol[k4 * 4 + 2], o);
            o = fmaf(r.w, wcol[k4 * 4 + 3], o);
        }
        __builtin_amdgcn_wave_barrier();
        o += bl;
        if (RELU) o = fmaxf(o, 0.f);
        Anext[(size_t)node * DIM + lane] = o;
    }
}

extern "C" void kernel_launch(void* const* d_in, const int* in_sizes, int n_in,
                              void* d_out, int out_size, void* d_ws, size_t ws_size,
                              hipStream_t stream) {
    const float* x  = (const float*)d_in[0];
    const int* ei   = (const int*)d_in[1];   // [2][NE] int32
    const float* ew = (const float*)d_in[2];
    const float* W1 = (const float*)d_in[3];
    const float* b1 = (const float*)d_in[4];
    const float* W2 = (const float*)d_in[5];
    const float* b2 = (const float*)d_in[6];
    const float* W3 = (const float*)d_in[7];
    const float* b3 = (const float*)d_in[8];
    float* out = (float*)d_out;

    const int* src = ei;
    const int* dst = ei + NE;

    auto align = [](size_t v) { return (v + 255) / 256 * 256; };
    char* ws = (char*)d_ws;
    int*   fill   = (int*)ws;   ws += align((size_t)NN * 4);
    float* dinv   = (float*)ws; ws += align((size_t)NN * 4);
    int2*  bucket = (int2*)ws;  ws += align((size_t)NN * CAP * 8);
    float* A      = (float*)ws;                      // one 25.6 MB intermediate

    const int gN = (NN + 255) / 256;
    const int gE = (NE + 255) / 256;
    const int gD = (NN * 16 + 255) / 256;
    const int gL = 2048;

    // ---- bucket CSR build: ONE atomic edge pass, no scan ----
    k_fill_init<<<gN, 256, 0, stream>>>(fill, NN);
    k_place<<<gE, 256, 0, stream>>>(src, dst, ew, fill, bucket, NE);
    k_deg<<<gD, 256, 0, stream>>>(bucket, fill, dinv, NN);

    // ---- fused layers (d_out doubles as layer-1 output) ----
    k_layer<1><<<gL, 256, 0, stream>>>(fill, bucket, x,   W1, b1, dinv, out, NN);
    k_layer<1><<<gL, 256, 0, stream>>>(fill, bucket, out, W2, b2, dinv, A,   NN);
    k_layer<0><<<gL, 256, 0, stream>>>(fill, bucket, A,   W3, b3, dinv, out, NN);
}

// Round 6
// 320.866 us; speedup vs baseline: 13.4453x; 1.1845x over previous
//
#include <hip/hip_runtime.h>

#define NN 100000
#define NE 1600000
#define DIM 64
#define NPB 128            // nodes per bin
#define NBIN 782           // ceil(NN / NPB)
#define NBINP 1024         // padded for scans
#define ECHUNK 2048        // edges per chunk
#define NCHUNKP 1024       // padded chunk count (real = 782)

// Per-chunk histogram over bins (LDS atomics only). gcounts layout: [bin][chunk].
__global__ __launch_bounds__(256) void k_hist(const int* __restrict__ dst,
                                              int* __restrict__ gcounts) {
    __shared__ int hist[NBINP];
    int tid = threadIdx.x, chunk = blockIdx.x;
    for (int j = tid; j < NBINP; j += 256) hist[j] = 0;
    __syncthreads();
    int base = chunk * ECHUNK;
    int lim = min(base + ECHUNK, NE);
    for (int i = base + tid; i < lim; i += 256)
        atomicAdd(&hist[dst[i] >> 7], 1);
    __syncthreads();
    for (int j = tid; j < NBINP; j += 256)
        gcounts[j * NCHUNKP + chunk] = hist[j];   // scattered 4B, 4MB L2-resident
}

// Per-bin exclusive scan over the chunk axis (row-contiguous, in place).
__global__ __launch_bounds__(256) void k_colscan(int* __restrict__ gcounts,
                                                 int* __restrict__ bintot) {
    __shared__ int sd[256];
    int t = threadIdx.x;
    int* p = gcounts + blockIdx.x * NCHUNKP;
    int v[4], s = 0;
    #pragma unroll
    for (int i = 0; i < 4; i++) { v[i] = p[t * 4 + i]; s += v[i]; }
    sd[t] = s;
    __syncthreads();
    for (int off = 1; off < 256; off <<= 1) {
        int x = (t >= off) ? sd[t - off] : 0;
        __syncthreads();
        sd[t] += x;
        __syncthreads();
    }
    int excl = sd[t] - s;
    #pragma unroll
    for (int i = 0; i < 4; i++) { p[t * 4 + i] = excl; excl += v[i]; }
    if (t == 255) bintot[blockIdx.x] = sd[255];
}

// Exclusive scan of 1024 bin totals -> binbase; also row_ptr[NN] = NE.
__global__ __launch_bounds__(256) void k_binscan(const int* __restrict__ bintot,
                                                 int* __restrict__ binbase,
                                                 int* __restrict__ row_ptr) {
    __shared__ int sd[256];
    int t = threadIdx.x;
    int v[4], s = 0;
    #pragma unroll
    for (int i = 0; i < 4; i++) { v[i] = bintot[t * 4 + i]; s += v[i]; }
    sd[t] = s;
    __syncthreads();
    for (int off = 1; off < 256; off <<= 1) {
        int x = (t >= off) ? sd[t - off] : 0;
        __syncthreads();
        sd[t] += x;
        __syncthreads();
    }
    int excl = sd[t] - s;
    #pragma unroll
    for (int i = 0; i < 4; i++) { binbase[t * 4 + i] = excl; excl += v[i]; }
    if (t == 255) { binbase[NBINP] = sd[255]; row_ptr[NN] = sd[255]; }
}

// Stable-ish scatter of edges into their bin's contiguous range. No global atomics.
// meta = src (17b) | dst_local (7b) << 17
__global__ __launch_bounds__(256) void k_scatbin(const int* __restrict__ src,
                                                 const int* __restrict__ dst,
                                                 const float* __restrict__ w,
                                                 const int* __restrict__ gcounts,
                                                 const int* __restrict__ binbase,
                                                 int2* __restrict__ binned) {
    __shared__ int lcur[NBINP];
    int tid = threadIdx.x, chunk = blockIdx.x;
    for (int j = tid; j < NBINP; j += 256) lcur[j] = 0;
    __syncthreads();
    int base = chunk * ECHUNK;
    int lim = min(base + ECHUNK, NE);
    for (int i = base + tid; i < lim; i += 256) {
        int d = dst[i];
        int b = d >> 7;
        int r = atomicAdd(&lcur[b], 1);                       // LDS atomic
        int pos = binbase[b] + gcounts[b * NCHUNKP + chunk] + r;
        int meta = src[i] | ((d & 127) << 17);
        binned[pos] = make_int2(meta, __float_as_int(w[i]));
    }
}

// Per-bin: exact per-node grouping + row_ptr + dinv. All LDS-local, contiguous I/O.
__global__ __launch_bounds__(256) void k_group(const int2* __restrict__ binned,
                                               const int* __restrict__ binbase,
                                               int2* __restrict__ edata,
                                               int* __restrict__ row_ptr,
                                               float* __restrict__ dinv) {
    __shared__ int ndeg[NPB];
    __shared__ float nws[NPB];
    __shared__ int ncur[NPB];
    __shared__ int sd[NPB];
    int t = threadIdx.x, bin = blockIdx.x;
    int beg = binbase[bin], end = binbase[bin + 1];
    if (t < NPB) { ndeg[t] = 0; nws[t] = 0.f; }
    __syncthreads();
    for (int e = beg + t; e < end; e += 256) {
        int2 v = binned[e];
        int dl = ((unsigned)v.x) >> 17;
        atomicAdd(&ndeg[dl], 1);
        atomicAdd(&nws[dl], __int_as_float(v.y));
    }
    __syncthreads();
    int own = 0;
    if (t < NPB) { own = ndeg[t]; sd[t] = own; }
    __syncthreads();
    for (int off = 1; off < NPB; off <<= 1) {
        int x = (t >= off && t < NPB) ? sd[t - off] : 0;
        __syncthreads();
        if (t < NPB) sd[t] += x;
        __syncthreads();
    }
    if (t < NPB) {
        int excl = sd[t] - own;
        ncur[t] = excl;
        int node = bin * NPB + t;
        if (node < NN) {
            row_ptr[node] = beg + excl;
            dinv[node] = rsqrtf(1.0f + nws[t]);
        }
    }
    __syncthreads();
    for (int e = beg + t; e < end; e += 256) {
        int2 v = binned[e];
        int dl = ((unsigned)v.x) >> 17;
        int r = atomicAdd(&ncur[dl], 1);
        edata[beg + r] = make_int2(v.x & 0x1FFFF, v.y);
    }
}

#define FMA4(acc, nm, h) \
    acc.x = fmaf(nm, h.x, acc.x); acc.y = fmaf(nm, h.y, acc.y); \
    acc.z = fmaf(nm, h.z, acc.z); acc.w = fmaf(nm, h.w, acc.w);

// Fused layer: OUT[v] = act( dinv[v]*(sum_e dinv[s]*w*Aprev[s] + dinv[v]*Aprev[v]) ) @ W + b
template <int RELU>
__global__ __launch_bounds__(256) void k_layer(const int* __restrict__ row_ptr,
                                               const int2* __restrict__ edata,
                                               const float* __restrict__ Aprev,
                                               const float* __restrict__ W,
                                               const float* __restrict__ bias,
                                               const float* __restrict__ dinv,
                                               float* __restrict__ Anext, int n) {
    __shared__ float rowbuf[4][64];
    int tid = threadIdx.x;
    int lane = tid & 63;
    int wv = tid >> 6;

    float wcol[64];
    #pragma unroll
    for (int k = 0; k < 64; k++) wcol[k] = W[k * 64 + lane];
    float bl = bias[lane];

    int g = lane >> 4;
    int l = lane & 15;

    int wave_id = blockIdx.x * 4 + wv;
    int nwaves = gridDim.x * 4;

    for (int node = wave_id; node < n; node += nwaves) {
        int beg = row_ptr[node], end = row_ptr[node + 1];
        float4 acc = make_float4(0.f, 0.f, 0.f, 0.f);

        int e = beg + g;
        for (; e + 12 < end; e += 16) {
            int2 e0 = edata[e];
            int2 e1 = edata[e + 4];
            int2 e2 = edata[e + 8];
            int2 e3 = edata[e + 12];
            float d0 = dinv[e0.x], d1 = dinv[e1.x], d2 = dinv[e2.x], d3 = dinv[e3.x];
            float4 h0 = *reinterpret_cast<const float4*>(Aprev + (size_t)e0.x * DIM + l * 4);
            float4 h1 = *reinterpret_cast<const float4*>(Aprev + (size_t)e1.x * DIM + l * 4);
            float4 h2 = *reinterpret_cast<const float4*>(Aprev + (size_t)e2.x * DIM + l * 4);
            float4 h3 = *reinterpret_cast<const float4*>(Aprev + (size_t)e3.x * DIM + l * 4);
            float n0 = d0 * __int_as_float(e0.y), n1 = d1 * __int_as_float(e1.y);
            float n2 = d2 * __int_as_float(e2.y), n3 = d3 * __int_as_float(e3.y);
            FMA4(acc, n0, h0); FMA4(acc, n1, h1);
            FMA4(acc, n2, h2); FMA4(acc, n3, h3);
        }
        for (; e + 4 < end; e += 8) {
            int2 e0 = edata[e];
            int2 e1 = edata[e + 4];
            float d0 = dinv[e0.x], d1 = dinv[e1.x];
            float4 h0 = *reinterpret_cast<const float4*>(Aprev + (size_t)e0.x * DIM + l * 4);
            float4 h1 = *reinterpret_cast<const float4*>(Aprev + (size_t)e1.x * DIM + l * 4);
            float n0 = d0 * __int_as_float(e0.y), n1 = d1 * __int_as_float(e1.y);
            FMA4(acc, n0, h0); FMA4(acc, n1, h1);
        }
        if (e < end) {
            int2 e0 = edata[e];
            float n0 = dinv[e0.x] * __int_as_float(e0.y);
            float4 h0 = *reinterpret_cast<const float4*>(Aprev + (size_t)e0.x * DIM + l * 4);
            FMA4(acc, n0, h0);
        }

        acc.x += __shfl_xor(acc.x, 16); acc.y += __shfl_xor(acc.y, 16);
        acc.z += __shfl_xor(acc.z, 16); acc.w += __shfl_xor(acc.w, 16);
        acc.x += __shfl_xor(acc.x, 32); acc.y += __shfl_xor(acc.y, 32);
        acc.z += __shfl_xor(acc.z, 32); acc.w += __shfl_xor(acc.w, 32);

        if (g == 0) {
            float dn = dinv[node];
            float4 sv = *reinterpret_cast<const float4*>(Aprev + (size_t)node * DIM + l * 4);
            acc.x = (fmaf(dn, sv.x, acc.x)) * dn;
            acc.y = (fmaf(dn, sv.y, acc.y)) * dn;
            acc.z = (fmaf(dn, sv.z, acc.z)) * dn;
            acc.w = (fmaf(dn, sv.w, acc.w)) * dn;
            *reinterpret_cast<float4*>(&rowbuf[wv][l * 4]) = acc;
        }
        __builtin_amdgcn_wave_barrier();

        float o = 0.f;
        #pragma unroll
        for (int k4 = 0; k4 < 16; k4++) {
            float4 r = *reinterpret_cast<const float4*>(&rowbuf[wv][k4 * 4]);
            o = fmaf(r.x, wcol[k4 * 4 + 0], o);
            o = fmaf(r.y, wcol[k4 * 4 + 1], o);
            o = fmaf(r.z, wcol[k4 * 4 + 2], o);
            o = fmaf(r.w, wcol[k4 * 4 + 3], o);
        }
        __builtin_amdgcn_wave_barrier();
        o += bl;
        if (RELU) o = fmaxf(o, 0.f);
        Anext[(size_t)node * DIM + lane] = o;
    }
}

extern "C" void kernel_launch(void* const* d_in, const int* in_sizes, int n_in,
                              void* d_out, int out_size, void* d_ws, size_t ws_size,
                              hipStream_t stream) {
    const float* x  = (const float*)d_in[0];
    const int* ei   = (const int*)d_in[1];   // [2][NE] int32
    const float* ew = (const float*)d_in[2];
    const float* W1 = (const float*)d_in[3];
    const float* b1 = (const float*)d_in[4];
    const float* W2 = (const float*)d_in[5];
    const float* b2 = (const float*)d_in[6];
    const float* W3 = (const float*)d_in[7];
    const float* b3 = (const float*)d_in[8];
    float* out = (float*)d_out;

    const int* src = ei;
    const int* dst = ei + NE;

    auto align = [](size_t v) { return (v + 255) / 256 * 256; };
    char* ws = (char*)d_ws;
    int*   gcounts = (int*)ws;  ws += align((size_t)NBINP * NCHUNKP * 4);  // 4 MB
    int*   bintot  = (int*)ws;  ws += align((size_t)NBINP * 4);
    int*   binbase = (int*)ws;  ws += align(((size_t)NBINP + 1) * 4);
    int*   row_ptr = (int*)ws;  ws += align(((size_t)NN + 1) * 4);
    float* dinv    = (float*)ws; ws += align((size_t)NN * 4);
    int2*  binned  = (int2*)ws; ws += align((size_t)NE * 8);               // 12.8 MB
    int2*  edata   = (int2*)ws; ws += align((size_t)NE * 8);               // 12.8 MB
    float* A       = (float*)ws;                                           // 25.6 MB

    const int gL = 2048;

    // ---- deterministic CSR build: zero global atomics ----
    k_hist<<<NCHUNKP, 256, 0, stream>>>(dst, gcounts);
    k_colscan<<<NBINP, 256, 0, stream>>>(gcounts, bintot);
    k_binscan<<<1, 256, 0, stream>>>(bintot, binbase, row_ptr);
    k_scatbin<<<NCHUNKP, 256, 0, stream>>>(src, dst, ew, gcounts, binbase, binned);
    k_group<<<NBIN, 256, 0, stream>>>(binned, binbase, edata, row_ptr, dinv);

    // ---- fused layers (d_out doubles as layer-1 output) ----
    k_layer<1><<<gL, 256, 0, stream>>>(row_ptr, edata, x,   W1, b1, dinv, out, NN);
    k_layer<1><<<gL, 256, 0, stream>>>(row_ptr, edata, out, W2, b2, dinv, A,   NN);
    k_layer<0><<<gL, 256, 0, stream>>>(row_ptr, edata, A,   W3, b3, dinv, out, NN);
}